// Round 1
// baseline (580.136 us; speedup 1.0000x reference)
//
#include <hip/hip_runtime.h>

#define TOKENS 4096
#define HIDDEN 4096
#define FFN    14336
#define R      16
#define SCALING 2.0f

// ---------------------------------------------------------------------------
// ws layout (floats):
//   w2aT : FFN*R        (929 KB)  transposed w2_A for contiguous reads
//   h13  : TOKENS*32    (512 KB)  [t][0..15]=x@w1_A.T+b, [16..31]=x@w3_A.T+b
//   h2   : TOKENS*R     (256 KB)  accumulated h@w2_A.T (atomics, zeroed/call)
// ---------------------------------------------------------------------------

__global__ __launch_bounds__(256) void k_transpose_w2a(
    const float* __restrict__ w2A, float* __restrict__ w2aT)
{
    int idx = blockIdx.x * 256 + threadIdx.x;   // over R*FFN, f-fastest: coalesced read
    if (idx < R * FFN) {
        int r = idx / FFN, f = idx % FFN;
        w2aT[(size_t)f * R + r] = w2A[idx];
    }
}

// K1: h13[t][rr] = dot(x[t,:], wA[rr,:]) + bias.  8 tokens/block, 32 dots each.
__global__ __launch_bounds__(256) void k1_xproj(
    const float* __restrict__ x,
    const float* __restrict__ w1A, const float* __restrict__ w1Ab,
    const float* __restrict__ w3A, const float* __restrict__ w3Ab,
    float* __restrict__ h13)
{
    __shared__ float xs[8][512];
    const int tid  = threadIdx.x;
    const int tloc = tid >> 5;     // 0..7 token within tile
    const int rr   = tid & 31;     // 0..31 output (16 for w1, 16 for w3)
    const int t0   = blockIdx.x * 8;

    const float* wrow = (rr < 16) ? (w1A + (size_t)rr * HIDDEN)
                                  : (w3A + (size_t)(rr - 16) * HIDDEN);
    float acc = 0.f;
    for (int hc = 0; hc < HIDDEN; hc += 512) {
        // stage x tile [8][512] coalesced: 1024 float4, 4 per thread
        #pragma unroll
        for (int k = 0; k < 4; ++k) {
            int gi  = tid + k * 256;          // 0..1023
            int row = gi >> 7;                // /128 float4s per row
            int c4  = gi & 127;
            float4 v = *reinterpret_cast<const float4*>(
                x + (size_t)(t0 + row) * HIDDEN + hc + c4 * 4);
            *reinterpret_cast<float4*>(&xs[row][c4 * 4]) = v;
        }
        __syncthreads();
        const float* wp = wrow + hc;
        #pragma unroll 4
        for (int hh = 0; hh < 512; hh += 4) {
            float4 xv = *reinterpret_cast<const float4*>(&xs[tloc][hh]);
            float4 wv = *reinterpret_cast<const float4*>(wp + hh);
            acc = fmaf(xv.x, wv.x, acc);
            acc = fmaf(xv.y, wv.y, acc);
            acc = fmaf(xv.z, wv.z, acc);
            acc = fmaf(xv.w, wv.w, acc);
        }
        __syncthreads();
    }
    float bias = (rr < 16) ? w1Ab[rr] : w3Ab[rr - 16];
    h13[(size_t)(t0 + tloc) * 32 + rr] = acc + bias;
}

// K2: the fused middle. Thread owns token t; block covers t-tile 256 x f-tile 512.
// Per f: g/u rank-16 dots, silu-gate, accumulate h*w2A into 16 regs. Atomic flush.
#define FBLK 512
#define SC   128

__global__ __launch_bounds__(256) void k2_mid(
    const float* __restrict__ h13,
    const float* __restrict__ w1B, const float* __restrict__ w1Bb,
    const float* __restrict__ w3B, const float* __restrict__ w3Bb,
    const float* __restrict__ w2aT,
    float* __restrict__ h2)
{
    __shared__ float s_w1b[SC * 16];
    __shared__ float s_w3b[SC * 16];
    __shared__ float s_w2a[SC * 16];
    __shared__ float s_b1[SC];
    __shared__ float s_b3[SC];

    const int tid = threadIdx.x;
    const int t   = blockIdx.x * 256 + tid;
    const int f0  = blockIdx.y * FBLK;

    float hA[16], hB[16], acc[16];
    {
        const float4* hp = reinterpret_cast<const float4*>(h13 + (size_t)t * 32);
        #pragma unroll
        for (int k = 0; k < 4; ++k) {
            float4 v = hp[k];
            hA[4*k+0] = v.x; hA[4*k+1] = v.y; hA[4*k+2] = v.z; hA[4*k+3] = v.w;
        }
        #pragma unroll
        for (int k = 0; k < 4; ++k) {
            float4 v = hp[4 + k];
            hB[4*k+0] = v.x; hB[4*k+1] = v.y; hB[4*k+2] = v.z; hB[4*k+3] = v.w;
        }
    }
    #pragma unroll
    for (int r = 0; r < 16; ++r) acc[r] = 0.f;

    for (int sc0 = 0; sc0 < FBLK; sc0 += SC) {
        const int fbase = f0 + sc0;
        const float4* g1 = reinterpret_cast<const float4*>(w1B  + (size_t)fbase * 16);
        const float4* g3 = reinterpret_cast<const float4*>(w3B  + (size_t)fbase * 16);
        const float4* g2 = reinterpret_cast<const float4*>(w2aT + (size_t)fbase * 16);
        __syncthreads();   // protect previous chunk's readers
        // stage 3 x (128x16 floats = 512 float4), 2 float4/thread each
        reinterpret_cast<float4*>(s_w1b)[tid]       = g1[tid];
        reinterpret_cast<float4*>(s_w1b)[tid + 256] = g1[tid + 256];
        reinterpret_cast<float4*>(s_w3b)[tid]       = g3[tid];
        reinterpret_cast<float4*>(s_w3b)[tid + 256] = g3[tid + 256];
        reinterpret_cast<float4*>(s_w2a)[tid]       = g2[tid];
        reinterpret_cast<float4*>(s_w2a)[tid + 256] = g2[tid + 256];
        if (tid < SC) {
            s_b1[tid] = w1Bb[fbase + tid];
            s_b3[tid] = w3Bb[fbase + tid];
        }
        __syncthreads();

        #pragma unroll 2
        for (int fl = 0; fl < SC; ++fl) {
            const float4* wb1 = reinterpret_cast<const float4*>(s_w1b + fl * 16);
            const float4* wb3 = reinterpret_cast<const float4*>(s_w3b + fl * 16);
            const float4* wa2 = reinterpret_cast<const float4*>(s_w2a + fl * 16);
            float g  = s_b1[fl];
            float uu = s_b3[fl];
            #pragma unroll
            for (int k = 0; k < 4; ++k) {
                float4 a = wb1[k];
                g = fmaf(hA[4*k+0], a.x, g);
                g = fmaf(hA[4*k+1], a.y, g);
                g = fmaf(hA[4*k+2], a.z, g);
                g = fmaf(hA[4*k+3], a.w, g);
            }
            #pragma unroll
            for (int k = 0; k < 4; ++k) {
                float4 a = wb3[k];
                uu = fmaf(hB[4*k+0], a.x, uu);
                uu = fmaf(hB[4*k+1], a.y, uu);
                uu = fmaf(hB[4*k+2], a.z, uu);
                uu = fmaf(hB[4*k+3], a.w, uu);
            }
            g  *= SCALING;
            uu *= SCALING;
            // silu(g)*u = g*sigmoid(g)*u ; v_rcp_f32 ~1ulp, plenty for 2% budget
            float sig = __builtin_amdgcn_rcpf(1.f + __expf(-g));
            float hv  = g * sig * uu;
            #pragma unroll
            for (int k = 0; k < 4; ++k) {
                float4 a = wa2[k];
                acc[4*k+0] = fmaf(hv, a.x, acc[4*k+0]);
                acc[4*k+1] = fmaf(hv, a.y, acc[4*k+1]);
                acc[4*k+2] = fmaf(hv, a.z, acc[4*k+2]);
                acc[4*k+3] = fmaf(hv, a.w, acc[4*k+3]);
            }
        }
    }
    #pragma unroll
    for (int r = 0; r < 16; ++r)
        atomicAdd(&h2[(size_t)t * 16 + r], acc[r]);
}

// K3: out[t][o] = (sum_r (h2[t][r]+w2Ab[r]) * w2B[o][r] + w2Bb[o]) * 2
__global__ __launch_bounds__(256) void k3_out(
    const float* __restrict__ h2,
    const float* __restrict__ w2Ab,
    const float* __restrict__ w2B, const float* __restrict__ w2Bb,
    float* __restrict__ out)
{
    __shared__ float s_h2[16][16];
    const int tid = threadIdx.x;
    const int t0  = blockIdx.x * 16;
    const int o0  = blockIdx.y * 1024;

    {
        int t = tid >> 4, r = tid & 15;
        s_h2[t][r] = h2[(size_t)(t0 + t) * 16 + r] + w2Ab[r];
    }
    __syncthreads();

    const int ob = o0 + tid * 4;
    float w[4][16];
    #pragma unroll
    for (int j = 0; j < 4; ++j) {
        #pragma unroll
        for (int k = 0; k < 4; ++k) {
            float4 v = *reinterpret_cast<const float4*>(
                w2B + (size_t)(ob + j) * 16 + k * 4);
            w[j][4*k+0] = v.x; w[j][4*k+1] = v.y;
            w[j][4*k+2] = v.z; w[j][4*k+3] = v.w;
        }
    }
    float4 bb = *reinterpret_cast<const float4*>(w2Bb + ob);
    float bias[4] = {bb.x, bb.y, bb.z, bb.w};

    for (int t = 0; t < 16; ++t) {
        float res[4];
        #pragma unroll
        for (int j = 0; j < 4; ++j) {
            float a = bias[j];
            #pragma unroll
            for (int r = 0; r < 16; ++r)
                a = fmaf(s_h2[t][r], w[j][r], a);
            res[j] = a * SCALING;
        }
        *reinterpret_cast<float4*>(out + (size_t)(t0 + t) * 4096 + ob) =
            make_float4(res[0], res[1], res[2], res[3]);
    }
}

extern "C" void kernel_launch(void* const* d_in, const int* in_sizes, int n_in,
                              void* d_out, int out_size, void* d_ws, size_t ws_size,
                              hipStream_t stream) {
    const float* x    = (const float*)d_in[0];
    const float* w1A  = (const float*)d_in[1];
    const float* w1Ab = (const float*)d_in[2];
    const float* w1B  = (const float*)d_in[3];
    const float* w1Bb = (const float*)d_in[4];
    const float* w3A  = (const float*)d_in[5];
    const float* w3Ab = (const float*)d_in[6];
    const float* w3B  = (const float*)d_in[7];
    const float* w3Bb = (const float*)d_in[8];
    const float* w2A  = (const float*)d_in[9];
    const float* w2Ab = (const float*)d_in[10];
    const float* w2B  = (const float*)d_in[11];
    const float* w2Bb = (const float*)d_in[12];
    float* out = (float*)d_out;

    float* ws   = (float*)d_ws;
    float* w2aT = ws;                          // FFN*R
    float* h13  = w2aT + (size_t)FFN * R;      // TOKENS*32
    float* h2   = h13 + (size_t)TOKENS * 32;   // TOKENS*R

    hipMemsetAsync(h2, 0, (size_t)TOKENS * R * sizeof(float), stream);
    k_transpose_w2a<<<(R * FFN + 255) / 256, 256, 0, stream>>>(w2A, w2aT);
    k1_xproj<<<TOKENS / 8, 256, 0, stream>>>(x, w1A, w1Ab, w3A, w3Ab, h13);
    k2_mid<<<dim3(TOKENS / 256, FFN / FBLK), 256, 0, stream>>>(
        h13, w1B, w1Bb, w3B, w3Bb, w2aT, h2);
    k3_out<<<dim3(TOKENS / 16, 4096 / 1024), 256, 0, stream>>>(
        h2, w2Ab, w2B, w2Bb, out);
}